// Round 2
// baseline (6471.532 us; speedup 1.0000x reference)
//
#include <hip/hip_runtime.h>
#include <math.h>

#define TT 1024
#define BB 256
#define DD 16
#define HH 128
#define CC 64

__device__ __forceinline__ float rcp_f(float x) { return __builtin_amdgcn_rcpf(x); }
__device__ __forceinline__ float spf(float x) {
  float e = __expf(-fabsf(x));
  return fmaxf(x, 0.0f) + __logf(1.0f + e);
}
__device__ __forceinline__ float sigf(float x) {
  return rcp_f(1.0f + __expf(-x));
}
__device__ __forceinline__ float tanh_f(float x) {
  float e = __expf(-2.0f * fabsf(x));
  float t = (1.0f - e) * rcp_f(1.0f + e);
  return x < 0.0f ? -t : t;
}

template<int NQ>
__device__ __forceinline__ float dotnq(const float4* w, const float* v) {
  float acc[4] = {0.f, 0.f, 0.f, 0.f};
  #pragma unroll
  for (int q = 0; q < NQ; ++q) {
    float4 vv = *(const float4*)(v + 4*q);
    acc[q & 3] = fmaf(w[q].x, vv.x, fmaf(w[q].y, vv.y,
                 fmaf(w[q].z, vv.z, fmaf(w[q].w, vv.w, acc[q & 3]))));
  }
  return (acc[0] + acc[1]) + (acc[2] + acc[3]);
}

// ---------------------------------------------------------------------------
// Encoder: backward GRU over T, fused ctx projection. One WG per batch elem.
// Thread j owns GRU row j (j<384). Whh row lives in VGPRs; h broadcast via LDS.
// ---------------------------------------------------------------------------
__global__ __launch_bounds__(384, 2) void enc_kernel(
    const float* __restrict__ xs, const float* __restrict__ Wih,
    const float* __restrict__ Whh, const float* __restrict__ bih,
    const float* __restrict__ bhh, const float* __restrict__ encW,
    const float* __restrict__ encB, float* __restrict__ ctx)
{
  const int b = blockIdx.x;
  const int j = threadIdx.x;
  __shared__ __align__(16) float hs[HH];
  __shared__ __align__(16) float xsh[DD];
  __shared__ __align__(16) float gsum[2*HH];
  __shared__ __align__(16) float gin[HH];
  __shared__ __align__(16) float ghn[HH];
  __shared__ float4 ew[32][CC];   // ew[k4][c] = encW[c][4k4..4k4+3]

  float4 wh[32];
  #pragma unroll
  for (int q = 0; q < 32; ++q) wh[q] = *(const float4*)(Whh + j*HH + 4*q);
  float4 wi[4];
  #pragma unroll
  for (int q = 0; q < 4; ++q) wi[q] = *(const float4*)(Wih + j*DD + 4*q);
  const float bi = bih[j];
  const float bh = bhh[j];
  const float eb = (j < CC) ? encB[j] : 0.0f;

  if (j < HH) hs[j] = 0.0f;
  for (int idx = j; idx < 32*CC; idx += 384) {
    int k4 = idx >> 6, c = idx & 63;
    ew[k4][c] = *(const float4*)(encW + c*HH + 4*k4);
  }
  if (j >= 368) xsh[j - 368] = xs[((size_t)(TT-1)*BB + b)*DD + (j - 368)];
  __syncthreads();

  for (int t = TT-1; t >= 0; --t) {
    // prefetch next x (t-1)
    float xnext = 0.0f;
    if (j >= 368) {
      int tm = (t > 0) ? (t - 1) : 0;
      xnext = xs[((size_t)tm*BB + b)*DD + (j - 368)];
    }
    // gi = bih + Wih row . x
    float gi = bi + dotnq<4>(wi, xsh);
    // gh = bhh + Whh row . h
    float gh = bh + dotnq<32>(wh, hs);
    if (j < 2*HH) gsum[j] = gi + gh;
    else { gin[j - 2*HH] = gi; ghn[j - 2*HH] = gh; }
    __syncthreads();   // A
    if (j < HH) {
      float rg = sigf(gsum[j]);
      float zg = sigf(gsum[HH + j]);
      float ng = tanh_f(gin[j] + rg * ghn[j]);
      hs[j] = (1.0f - zg) * ng + zg * hs[j];
    }
    if (j >= 368) xsh[j - 368] = xnext;
    __syncthreads();   // B
    if (j < CC) {
      float acc[4] = {0.f,0.f,0.f,0.f};
      #pragma unroll
      for (int q = 0; q < 32; ++q) {
        float4 hv = *(const float4*)(hs + 4*q);
        float4 wv = ew[q][j];
        acc[q & 3] = fmaf(wv.x, hv.x, fmaf(wv.y, hv.y,
                     fmaf(wv.z, hv.z, fmaf(wv.w, hv.w, acc[q & 3]))));
      }
      ctx[((size_t)t*BB + b)*CC + j] = eb + (acc[0]+acc[1]) + (acc[2]+acc[3]);
    }
  }
}

// ---------------------------------------------------------------------------
// Fused SDE scan: f-net, h-net, g-net all in one kernel. One WG per batch elem.
// 512 threads: role0/1 = f-net (+g half on role1), role2/3 = h-net (+g half).
// 5 barrier phases per step. logqp accumulated per-WG, one atomicAdd at end.
// ---------------------------------------------------------------------------
__global__ __launch_bounds__(512, 2) void sde_kernel(
    const float* __restrict__ xs, const float* __restrict__ tsv,
    const float* __restrict__ noise,
    const float* __restrict__ fW1, const float* __restrict__ fb1,
    const float* __restrict__ fW2, const float* __restrict__ fb2,
    const float* __restrict__ fW3, const float* __restrict__ fb3,
    const float* __restrict__ hW1, const float* __restrict__ hb1,
    const float* __restrict__ hW2, const float* __restrict__ hb2,
    const float* __restrict__ hW3, const float* __restrict__ hb3,
    const float* __restrict__ hW4, const float* __restrict__ hb4,
    const float* __restrict__ gW1, const float* __restrict__ gb1,
    const float* __restrict__ gW2, const float* __restrict__ gb2,
    const float* __restrict__ ctx, float* __restrict__ out)
{
  const int b = blockIdx.x;
  const int j = threadIdx.x;
  const int role = j >> 7;
  const int r = j & 127;
  const int l = j & 63;
  const int dq_d = l >> 2;
  const int dq_q = l & 3;

  __shared__ __align__(16) float zv[DD];
  __shared__ __align__(16) float ctxb[2][CC];
  __shared__ __align__(16) float x1[HH];
  __shared__ __align__(16) float p2[2][HH];
  __shared__ __align__(16) float x2s[HH];
  __shared__ __align__(16) float hx1[HH];
  __shared__ __align__(16) float hp[2][HH];
  __shared__ __align__(16) float hx2[HH];
  __shared__ __align__(16) float hq[2][HH];
  __shared__ __align__(16) float hx3[HH];
  __shared__ float w3c[HH][17];   // fW3 col-major, padded
  __shared__ float w4c[HH][17];   // hW4 col-major, padded
  __shared__ float gdpre[DD];

  float4 wa[20], wb[16], wg[6];
  #pragma unroll
  for (int q = 0; q < 20; ++q) wa[q] = make_float4(0.f,0.f,0.f,0.f);
  #pragma unroll
  for (int q = 0; q < 16; ++q) wb[q] = make_float4(0.f,0.f,0.f,0.f);
  #pragma unroll
  for (int q = 0; q < 6; ++q)  wg[q] = make_float4(0.f,0.f,0.f,0.f);

  float bA = 0.f, bB = 0.f;
  if (role == 0) {
    #pragma unroll
    for (int q = 0; q < 20; ++q) wa[q] = *(const float4*)(fW1 + r*80 + 4*q);
    #pragma unroll
    for (int q = 0; q < 16; ++q) wb[q] = *(const float4*)(fW2 + r*HH + 4*q);
    bA = fb1[r];
  } else if (role == 1) {
    #pragma unroll
    for (int q = 0; q < 16; ++q) wa[q] = *(const float4*)(fW2 + r*HH + 64 + 4*q);
    int d = r >> 4, h0 = (r & 15) * 8;
    #pragma unroll
    for (int m = 0; m < 2; ++m) {
      wg[m]     = *(const float4*)(gW1 + d*HH + h0 + 4*m);
      wg[2 + m] = *(const float4*)(gb1 + d*HH + h0 + 4*m);
      wg[4 + m] = *(const float4*)(gW2 + d*HH + h0 + 4*m);
    }
  } else if (role == 2) {
    #pragma unroll
    for (int q = 0; q < 4; ++q)  wa[q] = *(const float4*)(hW1 + r*DD + 4*q);
    #pragma unroll
    for (int q = 0; q < 16; ++q) wa[4+q] = *(const float4*)(hW2 + r*HH + 4*q);
    #pragma unroll
    for (int q = 0; q < 16; ++q) wb[q] = *(const float4*)(hW3 + r*HH + 4*q);
    bA = hb1[r]; bB = hb2[r];
  } else {
    #pragma unroll
    for (int q = 0; q < 16; ++q) wa[q] = *(const float4*)(hW2 + r*HH + 64 + 4*q);
    #pragma unroll
    for (int q = 0; q < 16; ++q) wb[q] = *(const float4*)(hW3 + r*HH + 64 + 4*q);
    int gidx = 128 + r; int d = gidx >> 4, h0 = (gidx & 15) * 8;
    #pragma unroll
    for (int m = 0; m < 2; ++m) {
      wg[m]     = *(const float4*)(gW1 + d*HH + h0 + 4*m);
      wg[2 + m] = *(const float4*)(gb1 + d*HH + h0 + 4*m);
      wg[4 + m] = *(const float4*)(gW2 + d*HH + h0 + 4*m);
    }
  }
  // wave0 extras (head biases)
  float f2ba=0.f, f2bb=0.f, h3ba=0.f, h3bb=0.f, fb3d=0.f, gb2d=0.f, hb4d=0.f;
  if (j < 64) {
    f2ba = fb2[2*l]; f2bb = fb2[2*l + 1];
    h3ba = hb3[2*l]; h3bb = hb3[2*l + 1];
    fb3d = fb3[dq_d]; gb2d = gb2[dq_d]; hb4d = hb4[dq_d];
  }
  // LDS fills
  if (role == 0) {
    #pragma unroll
    for (int d2 = 0; d2 < DD; ++d2) w3c[r][d2] = fW3[d2*HH + r];
  } else if (role == 1) {
    #pragma unroll
    for (int d2 = 0; d2 < DD; ++d2) w4c[r][d2] = hW4[d2*HH + r];
  }
  if (j < DD) zv[j] = xs[(size_t)b*DD + j];
  if (j < CC) ctxb[1][j] = ctx[((size_t)1*BB + b)*CC + j];

  const float dtc = tsv[1] - tsv[0];
  const float sdt = sqrtf(dtc);
  float nreg = 0.0f;
  if (j < 64 && dq_q == 0) nreg = noise[(size_t)b*DD + dq_d];
  float lqp = 0.0f;
  float fd_r = 0.f, gd_r = 0.f;
  __syncthreads();

  for (int i = 0; i < TT-1; ++i) {
    const int cur = (i + 1) & 1;
    const int nxt = i & 1;
    // ----- P0: f L1, h L1, g hidden; prefetch noise(i+1), ctx(i+2) -----
    float nnext = 0.0f;
    if (j < 64 && dq_q == 0 && (i + 1) < TT-1)
      nnext = noise[((size_t)(i+1)*BB + b)*DD + dq_d];
    float creg = 0.0f;
    if (role == 3 && r < CC) {
      int t2 = (i + 2 <= TT-1) ? (i + 2) : (TT-1);
      creg = ctx[((size_t)t2*BB + b)*CC + r];
    }
    if (role == 0) {
      float a = dotnq<4>(wa, zv) + dotnq<16>(wa + 4, ctxb[cur]);
      x1[r] = spf(bA + a);
    } else if (role == 2) {
      float a = dotnq<4>(wa, zv);
      hx1[r] = spf(bA + a);
    }
    if (role == 1 || role == 3) {
      int gidx = (role == 1) ? r : (128 + r);
      int d = gidx >> 4;
      float zd = zv[d];
      float ps = 0.f;
      #pragma unroll
      for (int m = 0; m < 2; ++m) {
        float4 w1v = wg[m], b1v = wg[2 + m], w2v = wg[4 + m];
        ps += spf(fmaf(zd, w1v.x, b1v.x)) * w2v.x;
        ps += spf(fmaf(zd, w1v.y, b1v.y)) * w2v.y;
        ps += spf(fmaf(zd, w1v.z, b1v.z)) * w2v.z;
        ps += spf(fmaf(zd, w1v.w, b1v.w)) * w2v.w;
      }
      ps += __shfl_xor(ps, 1);
      ps += __shfl_xor(ps, 2);
      ps += __shfl_xor(ps, 4);
      ps += __shfl_xor(ps, 8);
      if ((gidx & 15) == 0) gdpre[d] = ps;
    }
    __syncthreads();
    // ----- P1: f L2 halves, h L2 halves -----
    if (role == 0)      p2[0][r] = dotnq<16>(wb, x1);
    else if (role == 1) p2[1][r] = dotnq<16>(wa, x1 + 64);
    else if (role == 2) hp[0][r] = dotnq<16>(wa + 4, hx1);
    else                hp[1][r] = dotnq<16>(wa, hx1 + 64);
    __syncthreads();
    // ----- P2: x2 combine + fd head + z update (wave0); hx2 combine (s2) -----
    if (j < 64) {
      int r0 = 2*l, r1 = r0 + 1;
      float2 pa = *(const float2*)(&p2[0][r0]);
      float2 pb = *(const float2*)(&p2[1][r0]);
      x2s[r0] = spf(pa.x + pb.x + f2ba);
      x2s[r1] = spf(pa.y + pb.y + f2bb);
      float fa0 = 0.f, fa1 = 0.f;
      #pragma unroll
      for (int rr = 0; rr < 32; ++rr) {
        int ri = 4*rr + dq_q;
        if (rr & 1) fa1 = fmaf(w3c[ri][dq_d], x2s[ri], fa1);
        else        fa0 = fmaf(w3c[ri][dq_d], x2s[ri], fa0);
      }
      float facc = fa0 + fa1;
      facc += __shfl_xor(facc, 1);
      facc += __shfl_xor(facc, 2);
      if (dq_q == 0) {
        float fd = facc + fb3d;
        float gd = spf(gdpre[dq_d] + gb2d);
        float zpre = zv[dq_d];
        float znew = fmaf(fd, dtc, fmaf(gd, sdt * nreg, zpre));
        zv[dq_d] = znew;
        fd_r = fd; gd_r = gd;
        if (dq_d >= 8) {
          out[2 + ((size_t)(i+1)*BB + b)*8 + (dq_d - 8)] = znew;
          if (i == 0) out[2 + (size_t)b*8 + (dq_d - 8)] = zpre;
        }
      }
    } else if (role == 2) {
      hx2[r] = spf(hp[0][r] + hp[1][r] + bB);
    } else if (role == 3 && r < CC) {
      ctxb[nxt][r] = creg;
    }
    __syncthreads();
    // ----- P3: h L3 halves -----
    if (role == 2)      hq[0][r] = dotnq<16>(wb, hx2);
    else if (role == 3) hq[1][r] = dotnq<16>(wb, hx2 + 64);
    __syncthreads();
    // ----- P4: hx3 combine + hd head + u, dlq (wave0) -----
    if (j < 64) {
      int r0 = 2*l, r1 = r0 + 1;
      float2 qa = *(const float2*)(&hq[0][r0]);
      float2 qb = *(const float2*)(&hq[1][r0]);
      hx3[r0] = spf(qa.x + qb.x + h3ba);
      hx3[r1] = spf(qa.y + qb.y + h3bb);
      float ha0 = 0.f, ha1 = 0.f;
      #pragma unroll
      for (int rr = 0; rr < 32; ++rr) {
        int ri = 4*rr + dq_q;
        if (rr & 1) ha1 = fmaf(w4c[ri][dq_d], hx3[ri], ha1);
        else        ha0 = fmaf(w4c[ri][dq_d], hx3[ri], ha0);
      }
      float hacc = ha0 + ha1;
      hacc += __shfl_xor(hacc, 1);
      hacc += __shfl_xor(hacc, 2);
      if (dq_q == 0) {
        float hd = hacc + hb4d;
        float uu = (fd_r - hd) / (gd_r + 1e-7f);
        lqp = fmaf(0.5f * uu * uu, dtc, lqp);
      }
    }
    nreg = nnext;
    __syncthreads();
  }
  if (j < 64) {
    lqp += __shfl_xor(lqp, 1);
    lqp += __shfl_xor(lqp, 2);
    lqp += __shfl_xor(lqp, 4);
    lqp += __shfl_xor(lqp, 8);
    lqp += __shfl_xor(lqp, 16);
    lqp += __shfl_xor(lqp, 32);
    if (l == 0) atomicAdd(out + 1, lqp * (1.0f / 256.0f));
  }
}

// ---------------------------------------------------------------------------
// log_pxs reduction: sum over (t,b,o) of log_prob, / B. One block per t.
// ---------------------------------------------------------------------------
__global__ __launch_bounds__(256) void lp_kernel(const float* __restrict__ xs,
                                                 float* __restrict__ out)
{
  const int t = blockIdx.x;
  const int b = threadIdx.x;
  const float cst = 3.6862316527834183f;  // -log(0.01) - 0.5*log(2*pi)
  const float* xrow = xs + ((size_t)t*BB + b)*DD + 8;
  const float* zrow = out + 2 + ((size_t)t*BB + b)*8;
  float acc = 0.f;
  #pragma unroll
  for (int o = 0; o < 8; ++o) {
    float dd = (xrow[o] - zrow[o]) * 100.0f;
    acc += cst - 0.5f * dd * dd;
  }
  #pragma unroll
  for (int m = 1; m < 64; m <<= 1) acc += __shfl_xor(acc, m);
  __shared__ float wpart[4];
  int w = threadIdx.x >> 6;
  if ((threadIdx.x & 63) == 0) wpart[w] = acc;
  __syncthreads();
  if (threadIdx.x == 0)
    atomicAdd(out, (wpart[0] + wpart[1] + wpart[2] + wpart[3]) * (1.0f / 256.0f));
}

extern "C" void kernel_launch(void* const* d_in, const int* in_sizes, int n_in,
                              void* d_out, int out_size, void* d_ws, size_t ws_size,
                              hipStream_t stream) {
  const float* xs    = (const float*)d_in[0];
  const float* tsv   = (const float*)d_in[1];
  const float* noise = (const float*)d_in[2];
  const float* Wih   = (const float*)d_in[3];
  const float* Whh   = (const float*)d_in[4];
  const float* bih   = (const float*)d_in[5];
  const float* bhh   = (const float*)d_in[6];
  const float* encW  = (const float*)d_in[7];
  const float* encB  = (const float*)d_in[8];
  const float* fW1   = (const float*)d_in[9];
  const float* fb1   = (const float*)d_in[10];
  const float* fW2   = (const float*)d_in[11];
  const float* fb2   = (const float*)d_in[12];
  const float* fW3   = (const float*)d_in[13];
  const float* fb3   = (const float*)d_in[14];
  const float* hW1   = (const float*)d_in[15];
  const float* hb1   = (const float*)d_in[16];
  const float* hW2   = (const float*)d_in[17];
  const float* hb2   = (const float*)d_in[18];
  const float* hW3   = (const float*)d_in[19];
  const float* hb3   = (const float*)d_in[20];
  const float* hW4   = (const float*)d_in[21];
  const float* hb4   = (const float*)d_in[22];
  const float* gW1   = (const float*)d_in[23];
  const float* gb1   = (const float*)d_in[24];
  const float* gW2   = (const float*)d_in[25];
  const float* gb2   = (const float*)d_in[26];
  float* out = (float*)d_out;
  float* ctx = (float*)d_ws;   // T*B*C floats = 64 MiB

  hipMemsetAsync(d_out, 0, 2 * sizeof(float), stream);
  enc_kernel<<<BB, 384, 0, stream>>>(xs, Wih, Whh, bih, bhh, encW, encB, ctx);
  sde_kernel<<<BB, 512, 0, stream>>>(xs, tsv, noise,
                                     fW1, fb1, fW2, fb2, fW3, fb3,
                                     hW1, hb1, hW2, hb2, hW3, hb3, hW4, hb4,
                                     gW1, gb1, gW2, gb2, ctx, out);
  lp_kernel<<<TT, BB, 0, stream>>>(xs, out);
}

// Round 5
// 6458.157 us; speedup vs baseline: 1.0021x; 1.0021x over previous
//
#include <hip/hip_runtime.h>
#include <math.h>

#define TT 1024
#define BB 256
#define DD 16
#define HH 128
#define CC 64

__device__ __forceinline__ float rcp_f(float x) { return __builtin_amdgcn_rcpf(x); }
__device__ __forceinline__ float spf(float x) {
  float e = __expf(-fabsf(x));
  return fmaxf(x, 0.0f) + __logf(1.0f + e);
}
__device__ __forceinline__ float sigf(float x) {
  return rcp_f(1.0f + __expf(-x));
}
__device__ __forceinline__ float tanh_f(float x) {
  float e = __expf(-2.0f * fabsf(x));
  float t = (1.0f - e) * rcp_f(1.0f + e);
  return x < 0.0f ? -t : t;
}

template<int NQ>
__device__ __forceinline__ float dotnq(const float4* w, const float* v) {
  float acc[4] = {0.f, 0.f, 0.f, 0.f};
  #pragma unroll
  for (int q = 0; q < NQ; ++q) {
    float4 vv = *(const float4*)(v + 4*q);
    acc[q & 3] = fmaf(w[q].x, vv.x, fmaf(w[q].y, vv.y,
                 fmaf(w[q].z, vv.z, fmaf(w[q].w, vv.w, acc[q & 3]))));
  }
  return (acc[0] + acc[1]) + (acc[2] + acc[3]);
}

// ---------------------------------------------------------------------------
// Encoder: backward GRU over T, fused ctx projection. One WG per batch elem.
// Thread j owns GRU row j (j<384). Whh row lives in VGPRs; h broadcast via LDS.
// __launch_bounds__(384,1): 6-wave block = 2 waves/SIMD max -> 256 VGPR cap;
// weight arrays (~175 VGPR) must NOT spill (128-cap spilled in round 2).
// ---------------------------------------------------------------------------
__global__ __launch_bounds__(384, 1) void enc_kernel(
    const float* __restrict__ xs, const float* __restrict__ Wih,
    const float* __restrict__ Whh, const float* __restrict__ bih,
    const float* __restrict__ bhh, const float* __restrict__ encW,
    const float* __restrict__ encB, float* __restrict__ ctx)
{
  const int b = blockIdx.x;
  const int j = threadIdx.x;
  __shared__ __align__(16) float hs[HH];
  __shared__ __align__(16) float xsh[DD];
  __shared__ __align__(16) float gsum[2*HH];
  __shared__ __align__(16) float gin[HH];
  __shared__ __align__(16) float ghn[HH];
  __shared__ float4 ew[32][CC];   // ew[k4][c] = encW[c][4k4..4k4+3]

  float4 wh[32];
  #pragma unroll
  for (int q = 0; q < 32; ++q) wh[q] = *(const float4*)(Whh + j*HH + 4*q);
  float4 wi[4];
  #pragma unroll
  for (int q = 0; q < 4; ++q) wi[q] = *(const float4*)(Wih + j*DD + 4*q);
  const float bi = bih[j];
  const float bh = bhh[j];
  const float eb = (j < CC) ? encB[j] : 0.0f;

  if (j < HH) hs[j] = 0.0f;
  for (int idx = j; idx < 32*CC; idx += 384) {
    int k4 = idx >> 6, c = idx & 63;
    ew[k4][c] = *(const float4*)(encW + c*HH + 4*k4);
  }
  if (j >= 368) xsh[j - 368] = xs[((size_t)(TT-1)*BB + b)*DD + (j - 368)];
  __syncthreads();

  for (int t = TT-1; t >= 0; --t) {
    // prefetch next x (t-1)
    float xnext = 0.0f;
    if (j >= 368) {
      int tm = (t > 0) ? (t - 1) : 0;
      xnext = xs[((size_t)tm*BB + b)*DD + (j - 368)];
    }
    // gi = bih + Wih row . x
    float gi = bi + dotnq<4>(wi, xsh);
    // gh = bhh + Whh row . h
    float gh = bh + dotnq<32>(wh, hs);
    if (j < 2*HH) gsum[j] = gi + gh;
    else { gin[j - 2*HH] = gi; ghn[j - 2*HH] = gh; }
    __syncthreads();   // A
    if (j < HH) {
      float rg = sigf(gsum[j]);
      float zg = sigf(gsum[HH + j]);
      float ng = tanh_f(gin[j] + rg * ghn[j]);
      hs[j] = (1.0f - zg) * ng + zg * hs[j];
    }
    if (j >= 368) xsh[j - 368] = xnext;
    __syncthreads();   // B
    if (j < CC) {
      float acc[4] = {0.f,0.f,0.f,0.f};
      #pragma unroll
      for (int q = 0; q < 32; ++q) {
        float4 hv = *(const float4*)(hs + 4*q);
        float4 wv = ew[q][j];
        acc[q & 3] = fmaf(wv.x, hv.x, fmaf(wv.y, hv.y,
                     fmaf(wv.z, hv.z, fmaf(wv.w, hv.w, acc[q & 3]))));
      }
      ctx[((size_t)t*BB + b)*CC + j] = eb + (acc[0]+acc[1]) + (acc[2]+acc[3]);
    }
  }
}

// ---------------------------------------------------------------------------
// Fused SDE scan: f-net, h-net, g-net all in one kernel. One WG per batch elem.
// 512 threads: role0/1 = f-net (+g half on role1), role2/3 = h-net (+g half).
// 5 barrier phases per step. logqp accumulated per-WG, one atomicAdd at end.
// __launch_bounds__(512,1): 8-wave block = 2 waves/SIMD -> 256 VGPR cap; the
// ~210-VGPR weight-resident working set must not spill (round-2 lesson).
// ---------------------------------------------------------------------------
__global__ __launch_bounds__(512, 1) void sde_kernel(
    const float* __restrict__ xs, const float* __restrict__ tsv,
    const float* __restrict__ noise,
    const float* __restrict__ fW1, const float* __restrict__ fb1,
    const float* __restrict__ fW2, const float* __restrict__ fb2,
    const float* __restrict__ fW3, const float* __restrict__ fb3,
    const float* __restrict__ hW1, const float* __restrict__ hb1,
    const float* __restrict__ hW2, const float* __restrict__ hb2,
    const float* __restrict__ hW3, const float* __restrict__ hb3,
    const float* __restrict__ hW4, const float* __restrict__ hb4,
    const float* __restrict__ gW1, const float* __restrict__ gb1,
    const float* __restrict__ gW2, const float* __restrict__ gb2,
    const float* __restrict__ ctx, float* __restrict__ out)
{
  const int b = blockIdx.x;
  const int j = threadIdx.x;
  const int role = j >> 7;
  const int r = j & 127;
  const int l = j & 63;
  const int dq_d = l >> 2;
  const int dq_q = l & 3;

  __shared__ __align__(16) float zv[DD];
  __shared__ __align__(16) float ctxb[2][CC];
  __shared__ __align__(16) float x1[HH];
  __shared__ __align__(16) float p2[2][HH];
  __shared__ __align__(16) float x2s[HH];
  __shared__ __align__(16) float hx1[HH];
  __shared__ __align__(16) float hp[2][HH];
  __shared__ __align__(16) float hx2[HH];
  __shared__ __align__(16) float hq[2][HH];
  __shared__ __align__(16) float hx3[HH];
  __shared__ float w3c[HH][17];   // fW3 col-major, padded
  __shared__ float w4c[HH][17];   // hW4 col-major, padded
  __shared__ float gdpre[DD];

  float4 wa[20], wb[16], wg[6];
  #pragma unroll
  for (int q = 0; q < 20; ++q) wa[q] = make_float4(0.f,0.f,0.f,0.f);
  #pragma unroll
  for (int q = 0; q < 16; ++q) wb[q] = make_float4(0.f,0.f,0.f,0.f);
  #pragma unroll
  for (int q = 0; q < 6; ++q)  wg[q] = make_float4(0.f,0.f,0.f,0.f);

  float bA = 0.f, bB = 0.f;
  if (role == 0) {
    #pragma unroll
    for (int q = 0; q < 20; ++q) wa[q] = *(const float4*)(fW1 + r*80 + 4*q);
    #pragma unroll
    for (int q = 0; q < 16; ++q) wb[q] = *(const float4*)(fW2 + r*HH + 4*q);
    bA = fb1[r];
  } else if (role == 1) {
    #pragma unroll
    for (int q = 0; q < 16; ++q) wa[q] = *(const float4*)(fW2 + r*HH + 64 + 4*q);
    int d = r >> 4, h0 = (r & 15) * 8;
    #pragma unroll
    for (int m = 0; m < 2; ++m) {
      wg[m]     = *(const float4*)(gW1 + d*HH + h0 + 4*m);
      wg[2 + m] = *(const float4*)(gb1 + d*HH + h0 + 4*m);
      wg[4 + m] = *(const float4*)(gW2 + d*HH + h0 + 4*m);
    }
  } else if (role == 2) {
    #pragma unroll
    for (int q = 0; q < 4; ++q)  wa[q] = *(const float4*)(hW1 + r*DD + 4*q);
    #pragma unroll
    for (int q = 0; q < 16; ++q) wa[4+q] = *(const float4*)(hW2 + r*HH + 4*q);
    #pragma unroll
    for (int q = 0; q < 16; ++q) wb[q] = *(const float4*)(hW3 + r*HH + 4*q);
    bA = hb1[r]; bB = hb2[r];
  } else {
    #pragma unroll
    for (int q = 0; q < 16; ++q) wa[q] = *(const float4*)(hW2 + r*HH + 64 + 4*q);
    #pragma unroll
    for (int q = 0; q < 16; ++q) wb[q] = *(const float4*)(hW3 + r*HH + 64 + 4*q);
    int gidx = 128 + r; int d = gidx >> 4, h0 = (gidx & 15) * 8;
    #pragma unroll
    for (int m = 0; m < 2; ++m) {
      wg[m]     = *(const float4*)(gW1 + d*HH + h0 + 4*m);
      wg[2 + m] = *(const float4*)(gb1 + d*HH + h0 + 4*m);
      wg[4 + m] = *(const float4*)(gW2 + d*HH + h0 + 4*m);
    }
  }
  // wave0 extras (head biases)
  float f2ba=0.f, f2bb=0.f, h3ba=0.f, h3bb=0.f, fb3d=0.f, gb2d=0.f, hb4d=0.f;
  if (j < 64) {
    f2ba = fb2[2*l]; f2bb = fb2[2*l + 1];
    h3ba = hb3[2*l]; h3bb = hb3[2*l + 1];
    fb3d = fb3[dq_d]; gb2d = gb2[dq_d]; hb4d = hb4[dq_d];
  }
  // LDS fills
  if (role == 0) {
    #pragma unroll
    for (int d2 = 0; d2 < DD; ++d2) w3c[r][d2] = fW3[d2*HH + r];
  } else if (role == 1) {
    #pragma unroll
    for (int d2 = 0; d2 < DD; ++d2) w4c[r][d2] = hW4[d2*HH + r];
  }
  if (j < DD) zv[j] = xs[(size_t)b*DD + j];
  if (j < CC) ctxb[1][j] = ctx[((size_t)1*BB + b)*CC + j];

  const float dtc = tsv[1] - tsv[0];
  const float sdt = sqrtf(dtc);
  float nreg = 0.0f;
  if (j < 64 && dq_q == 0) nreg = noise[(size_t)b*DD + dq_d];
  float lqp = 0.0f;
  float fd_r = 0.f, gd_r = 0.f;
  __syncthreads();

  for (int i = 0; i < TT-1; ++i) {
    const int cur = (i + 1) & 1;
    const int nxt = i & 1;
    // ----- P0: f L1, h L1, g hidden; prefetch noise(i+1), ctx(i+2) -----
    float nnext = 0.0f;
    if (j < 64 && dq_q == 0 && (i + 1) < TT-1)
      nnext = noise[((size_t)(i+1)*BB + b)*DD + dq_d];
    float creg = 0.0f;
    if (role == 3 && r < CC) {
      int t2 = (i + 2 <= TT-1) ? (i + 2) : (TT-1);
      creg = ctx[((size_t)t2*BB + b)*CC + r];
    }
    if (role == 0) {
      float a = dotnq<4>(wa, zv) + dotnq<16>(wa + 4, ctxb[cur]);
      x1[r] = spf(bA + a);
    } else if (role == 2) {
      float a = dotnq<4>(wa, zv);
      hx1[r] = spf(bA + a);
    }
    if (role == 1 || role == 3) {
      int gidx = (role == 1) ? r : (128 + r);
      int d = gidx >> 4;
      float zd = zv[d];
      float ps = 0.f;
      #pragma unroll
      for (int m = 0; m < 2; ++m) {
        float4 w1v = wg[m], b1v = wg[2 + m], w2v = wg[4 + m];
        ps += spf(fmaf(zd, w1v.x, b1v.x)) * w2v.x;
        ps += spf(fmaf(zd, w1v.y, b1v.y)) * w2v.y;
        ps += spf(fmaf(zd, w1v.z, b1v.z)) * w2v.z;
        ps += spf(fmaf(zd, w1v.w, b1v.w)) * w2v.w;
      }
      ps += __shfl_xor(ps, 1);
      ps += __shfl_xor(ps, 2);
      ps += __shfl_xor(ps, 4);
      ps += __shfl_xor(ps, 8);
      if ((gidx & 15) == 0) gdpre[d] = ps;
    }
    __syncthreads();
    // ----- P1: f L2 halves, h L2 halves -----
    if (role == 0)      p2[0][r] = dotnq<16>(wb, x1);
    else if (role == 1) p2[1][r] = dotnq<16>(wa, x1 + 64);
    else if (role == 2) hp[0][r] = dotnq<16>(wa + 4, hx1);
    else                hp[1][r] = dotnq<16>(wa, hx1 + 64);
    __syncthreads();
    // ----- P2: x2 combine + fd head + z update (wave0); hx2 combine (s2) -----
    if (j < 64) {
      int r0 = 2*l, r1 = r0 + 1;
      float2 pa = *(const float2*)(&p2[0][r0]);
      float2 pb = *(const float2*)(&p2[1][r0]);
      x2s[r0] = spf(pa.x + pb.x + f2ba);
      x2s[r1] = spf(pa.y + pb.y + f2bb);
      float fa0 = 0.f, fa1 = 0.f;
      #pragma unroll
      for (int rr = 0; rr < 32; ++rr) {
        int ri = 4*rr + dq_q;
        if (rr & 1) fa1 = fmaf(w3c[ri][dq_d], x2s[ri], fa1);
        else        fa0 = fmaf(w3c[ri][dq_d], x2s[ri], fa0);
      }
      float facc = fa0 + fa1;
      facc += __shfl_xor(facc, 1);
      facc += __shfl_xor(facc, 2);
      if (dq_q == 0) {
        float fd = facc + fb3d;
        float gd = spf(gdpre[dq_d] + gb2d);
        float zpre = zv[dq_d];
        float znew = fmaf(fd, dtc, fmaf(gd, sdt * nreg, zpre));
        zv[dq_d] = znew;
        fd_r = fd; gd_r = gd;
        if (dq_d >= 8) {
          out[2 + ((size_t)(i+1)*BB + b)*8 + (dq_d - 8)] = znew;
          if (i == 0) out[2 + (size_t)b*8 + (dq_d - 8)] = zpre;
        }
      }
    } else if (role == 2) {
      hx2[r] = spf(hp[0][r] + hp[1][r] + bB);
    } else if (role == 3 && r < CC) {
      ctxb[nxt][r] = creg;
    }
    __syncthreads();
    // ----- P3: h L3 halves -----
    if (role == 2)      hq[0][r] = dotnq<16>(wb, hx2);
    else if (role == 3) hq[1][r] = dotnq<16>(wb, hx2 + 64);
    __syncthreads();
    // ----- P4: hx3 combine + hd head + u, dlq (wave0) -----
    if (j < 64) {
      int r0 = 2*l, r1 = r0 + 1;
      float2 qa = *(const float2*)(&hq[0][r0]);
      float2 qb = *(const float2*)(&hq[1][r0]);
      hx3[r0] = spf(qa.x + qb.x + h3ba);
      hx3[r1] = spf(qa.y + qb.y + h3bb);
      float ha0 = 0.f, ha1 = 0.f;
      #pragma unroll
      for (int rr = 0; rr < 32; ++rr) {
        int ri = 4*rr + dq_q;
        if (rr & 1) ha1 = fmaf(w4c[ri][dq_d], hx3[ri], ha1);
        else        ha0 = fmaf(w4c[ri][dq_d], hx3[ri], ha0);
      }
      float hacc = ha0 + ha1;
      hacc += __shfl_xor(hacc, 1);
      hacc += __shfl_xor(hacc, 2);
      if (dq_q == 0) {
        float hd = hacc + hb4d;
        float uu = (fd_r - hd) / (gd_r + 1e-7f);
        lqp = fmaf(0.5f * uu * uu, dtc, lqp);
      }
    }
    nreg = nnext;
    __syncthreads();
  }
  if (j < 64) {
    lqp += __shfl_xor(lqp, 1);
    lqp += __shfl_xor(lqp, 2);
    lqp += __shfl_xor(lqp, 4);
    lqp += __shfl_xor(lqp, 8);
    lqp += __shfl_xor(lqp, 16);
    lqp += __shfl_xor(lqp, 32);
    if (l == 0) atomicAdd(out + 1, lqp * (1.0f / 256.0f));
  }
}

// ---------------------------------------------------------------------------
// log_pxs reduction: sum over (t,b,o) of log_prob, / B. One block per t.
// ---------------------------------------------------------------------------
__global__ __launch_bounds__(256) void lp_kernel(const float* __restrict__ xs,
                                                 float* __restrict__ out)
{
  const int t = blockIdx.x;
  const int b = threadIdx.x;
  const float cst = 3.6862316527834183f;  // -log(0.01) - 0.5*log(2*pi)
  const float* xrow = xs + ((size_t)t*BB + b)*DD + 8;
  const float* zrow = out + 2 + ((size_t)t*BB + b)*8;
  float acc = 0.f;
  #pragma unroll
  for (int o = 0; o < 8; ++o) {
    float dd = (xrow[o] - zrow[o]) * 100.0f;
    acc += cst - 0.5f * dd * dd;
  }
  #pragma unroll
  for (int m = 1; m < 64; m <<= 1) acc += __shfl_xor(acc, m);
  __shared__ float wpart[4];
  int w = threadIdx.x >> 6;
  if ((threadIdx.x & 63) == 0) wpart[w] = acc;
  __syncthreads();
  if (threadIdx.x == 0)
    atomicAdd(out, (wpart[0] + wpart[1] + wpart[2] + wpart[3]) * (1.0f / 256.0f));
}

extern "C" void kernel_launch(void* const* d_in, const int* in_sizes, int n_in,
                              void* d_out, int out_size, void* d_ws, size_t ws_size,
                              hipStream_t stream) {
  const float* xs    = (const float*)d_in[0];
  const float* tsv   = (const float*)d_in[1];
  const float* noise = (const float*)d_in[2];
  const float* Wih   = (const float*)d_in[3];
  const float* Whh   = (const float*)d_in[4];
  const float* bih   = (const float*)d_in[5];
  const float* bhh   = (const float*)d_in[6];
  const float* encW  = (const float*)d_in[7];
  const float* encB  = (const float*)d_in[8];
  const float* fW1   = (const float*)d_in[9];
  const float* fb1   = (const float*)d_in[10];
  const float* fW2   = (const float*)d_in[11];
  const float* fb2   = (const float*)d_in[12];
  const float* fW3   = (const float*)d_in[13];
  const float* fb3   = (const float*)d_in[14];
  const float* hW1   = (const float*)d_in[15];
  const float* hb1   = (const float*)d_in[16];
  const float* hW2   = (const float*)d_in[17];
  const float* hb2   = (const float*)d_in[18];
  const float* hW3   = (const float*)d_in[19];
  const float* hb3   = (const float*)d_in[20];
  const float* hW4   = (const float*)d_in[21];
  const float* hb4   = (const float*)d_in[22];
  const float* gW1   = (const float*)d_in[23];
  const float* gb1   = (const float*)d_in[24];
  const float* gW2   = (const float*)d_in[25];
  const float* gb2   = (const float*)d_in[26];
  float* out = (float*)d_out;
  float* ctx = (float*)d_ws;   // T*B*C floats = 64 MiB

  hipMemsetAsync(d_out, 0, 2 * sizeof(float), stream);
  enc_kernel<<<BB, 384, 0, stream>>>(xs, Wih, Whh, bih, bhh, encW, encB, ctx);
  sde_kernel<<<BB, 512, 0, stream>>>(xs, tsv, noise,
                                     fW1, fb1, fW2, fb2, fW3, fb3,
                                     hW1, hb1, hW2, hb2, hW3, hb3, hW4, hb4,
                                     gW1, gb1, gW2, gb2, ctx, out);
  lp_kernel<<<TT, BB, 0, stream>>>(xs, out);
}

// Round 6
// 6452.295 us; speedup vs baseline: 1.0030x; 1.0009x over previous
//
#include <hip/hip_runtime.h>
#include <math.h>

#define TT 1024
#define BB 256
#define DD 16
#define HH 128
#define CC 64

__device__ __forceinline__ float rcp_f(float x) { return __builtin_amdgcn_rcpf(x); }
__device__ __forceinline__ float spf(float x) {
  float e = __expf(-fabsf(x));
  return fmaxf(x, 0.0f) + __logf(1.0f + e);
}
__device__ __forceinline__ float sigf(float x) {
  return rcp_f(1.0f + __expf(-x));
}
__device__ __forceinline__ float tanh_f(float x) {
  float e = __expf(-2.0f * fabsf(x));
  float t = (1.0f - e) * rcp_f(1.0f + e);
  return x < 0.0f ? -t : t;
}

template<int NQ>
__device__ __forceinline__ float dotnq(const float4* w, const float* v) {
  float acc[4] = {0.f, 0.f, 0.f, 0.f};
  #pragma unroll
  for (int q = 0; q < NQ; ++q) {
    float4 vv = *(const float4*)(v + 4*q);
    acc[q & 3] = fmaf(w[q].x, vv.x, fmaf(w[q].y, vv.y,
                 fmaf(w[q].z, vv.z, fmaf(w[q].w, vv.w, acc[q & 3]))));
  }
  return (acc[0] + acc[1]) + (acc[2] + acc[3]);
}

// ---------------------------------------------------------------------------
// Encoder: backward GRU over T, fused ctx projection. One WG per batch elem.
// Thread j owns GRU row j (j<384). Whh row lives in VGPRs; h broadcast via LDS.
// amdgpu_waves_per_eu(1,2): RA VGPR budget from min-occupancy=1 wave/EU ->
// up to 512 VGPR/wave; weight arrays (~175 VGPR) must NOT spill.
// (__launch_bounds__ 2nd arg was ignored: rounds 2 & 5 both capped at 128.)
// ---------------------------------------------------------------------------
__global__
__attribute__((amdgpu_flat_work_group_size(384, 384), amdgpu_waves_per_eu(1, 2)))
void enc_kernel(
    const float* __restrict__ xs, const float* __restrict__ Wih,
    const float* __restrict__ Whh, const float* __restrict__ bih,
    const float* __restrict__ bhh, const float* __restrict__ encW,
    const float* __restrict__ encB, float* __restrict__ ctx)
{
  const int b = blockIdx.x;
  const int j = threadIdx.x;
  __shared__ __align__(16) float hs[HH];
  __shared__ __align__(16) float xsh[DD];
  __shared__ __align__(16) float gsum[2*HH];
  __shared__ __align__(16) float gin[HH];
  __shared__ __align__(16) float ghn[HH];
  __shared__ float4 ew[32][CC];   // ew[k4][c] = encW[c][4k4..4k4+3]

  float4 wh[32];
  #pragma unroll
  for (int q = 0; q < 32; ++q) wh[q] = *(const float4*)(Whh + j*HH + 4*q);
  float4 wi[4];
  #pragma unroll
  for (int q = 0; q < 4; ++q) wi[q] = *(const float4*)(Wih + j*DD + 4*q);
  const float bi = bih[j];
  const float bh = bhh[j];
  const float eb = (j < CC) ? encB[j] : 0.0f;

  if (j < HH) hs[j] = 0.0f;
  for (int idx = j; idx < 32*CC; idx += 384) {
    int k4 = idx >> 6, c = idx & 63;
    ew[k4][c] = *(const float4*)(encW + c*HH + 4*k4);
  }
  if (j >= 368) xsh[j - 368] = xs[((size_t)(TT-1)*BB + b)*DD + (j - 368)];
  __syncthreads();

  for (int t = TT-1; t >= 0; --t) {
    // prefetch next x (t-1)
    float xnext = 0.0f;
    if (j >= 368) {
      int tm = (t > 0) ? (t - 1) : 0;
      xnext = xs[((size_t)tm*BB + b)*DD + (j - 368)];
    }
    // gi = bih + Wih row . x
    float gi = bi + dotnq<4>(wi, xsh);
    // gh = bhh + Whh row . h
    float gh = bh + dotnq<32>(wh, hs);
    if (j < 2*HH) gsum[j] = gi + gh;
    else { gin[j - 2*HH] = gi; ghn[j - 2*HH] = gh; }
    __syncthreads();   // A
    if (j < HH) {
      float rg = sigf(gsum[j]);
      float zg = sigf(gsum[HH + j]);
      float ng = tanh_f(gin[j] + rg * ghn[j]);
      hs[j] = (1.0f - zg) * ng + zg * hs[j];
    }
    if (j >= 368) xsh[j - 368] = xnext;
    __syncthreads();   // B
    if (j < CC) {
      float acc[4] = {0.f,0.f,0.f,0.f};
      #pragma unroll
      for (int q = 0; q < 32; ++q) {
        float4 hv = *(const float4*)(hs + 4*q);
        float4 wv = ew[q][j];
        acc[q & 3] = fmaf(wv.x, hv.x, fmaf(wv.y, hv.y,
                     fmaf(wv.z, hv.z, fmaf(wv.w, hv.w, acc[q & 3]))));
      }
      ctx[((size_t)t*BB + b)*CC + j] = eb + (acc[0]+acc[1]) + (acc[2]+acc[3]);
    }
  }
}

// ---------------------------------------------------------------------------
// Fused SDE scan: f-net, h-net, g-net all in one kernel. One WG per batch elem.
// 512 threads: role0/1 = f-net (+g half on role1), role2/3 = h-net (+g half).
// 5 barrier phases per step. logqp accumulated per-WG, one atomicAdd at end.
// amdgpu_waves_per_eu(1,2): lift the RA's default 4-waves/EU target (which
// capped VGPR at 128 and spilled the ~210-VGPR weight-resident working set).
// ---------------------------------------------------------------------------
__global__
__attribute__((amdgpu_flat_work_group_size(512, 512), amdgpu_waves_per_eu(1, 2)))
void sde_kernel(
    const float* __restrict__ xs, const float* __restrict__ tsv,
    const float* __restrict__ noise,
    const float* __restrict__ fW1, const float* __restrict__ fb1,
    const float* __restrict__ fW2, const float* __restrict__ fb2,
    const float* __restrict__ fW3, const float* __restrict__ fb3,
    const float* __restrict__ hW1, const float* __restrict__ hb1,
    const float* __restrict__ hW2, const float* __restrict__ hb2,
    const float* __restrict__ hW3, const float* __restrict__ hb3,
    const float* __restrict__ hW4, const float* __restrict__ hb4,
    const float* __restrict__ gW1, const float* __restrict__ gb1,
    const float* __restrict__ gW2, const float* __restrict__ gb2,
    const float* __restrict__ ctx, float* __restrict__ out)
{
  const int b = blockIdx.x;
  const int j = threadIdx.x;
  const int role = j >> 7;
  const int r = j & 127;
  const int l = j & 63;
  const int dq_d = l >> 2;
  const int dq_q = l & 3;

  __shared__ __align__(16) float zv[DD];
  __shared__ __align__(16) float ctxb[2][CC];
  __shared__ __align__(16) float x1[HH];
  __shared__ __align__(16) float p2[2][HH];
  __shared__ __align__(16) float x2s[HH];
  __shared__ __align__(16) float hx1[HH];
  __shared__ __align__(16) float hp[2][HH];
  __shared__ __align__(16) float hx2[HH];
  __shared__ __align__(16) float hq[2][HH];
  __shared__ __align__(16) float hx3[HH];
  __shared__ float w3c[HH][17];   // fW3 col-major, padded
  __shared__ float w4c[HH][17];   // hW4 col-major, padded
  __shared__ float gdpre[DD];

  float4 wa[20], wb[16], wg[6];
  #pragma unroll
  for (int q = 0; q < 20; ++q) wa[q] = make_float4(0.f,0.f,0.f,0.f);
  #pragma unroll
  for (int q = 0; q < 16; ++q) wb[q] = make_float4(0.f,0.f,0.f,0.f);
  #pragma unroll
  for (int q = 0; q < 6; ++q)  wg[q] = make_float4(0.f,0.f,0.f,0.f);

  float bA = 0.f, bB = 0.f;
  if (role == 0) {
    #pragma unroll
    for (int q = 0; q < 20; ++q) wa[q] = *(const float4*)(fW1 + r*80 + 4*q);
    #pragma unroll
    for (int q = 0; q < 16; ++q) wb[q] = *(const float4*)(fW2 + r*HH + 4*q);
    bA = fb1[r];
  } else if (role == 1) {
    #pragma unroll
    for (int q = 0; q < 16; ++q) wa[q] = *(const float4*)(fW2 + r*HH + 64 + 4*q);
    int d = r >> 4, h0 = (r & 15) * 8;
    #pragma unroll
    for (int m = 0; m < 2; ++m) {
      wg[m]     = *(const float4*)(gW1 + d*HH + h0 + 4*m);
      wg[2 + m] = *(const float4*)(gb1 + d*HH + h0 + 4*m);
      wg[4 + m] = *(const float4*)(gW2 + d*HH + h0 + 4*m);
    }
  } else if (role == 2) {
    #pragma unroll
    for (int q = 0; q < 4; ++q)  wa[q] = *(const float4*)(hW1 + r*DD + 4*q);
    #pragma unroll
    for (int q = 0; q < 16; ++q) wa[4+q] = *(const float4*)(hW2 + r*HH + 4*q);
    #pragma unroll
    for (int q = 0; q < 16; ++q) wb[q] = *(const float4*)(hW3 + r*HH + 4*q);
    bA = hb1[r]; bB = hb2[r];
  } else {
    #pragma unroll
    for (int q = 0; q < 16; ++q) wa[q] = *(const float4*)(hW2 + r*HH + 64 + 4*q);
    #pragma unroll
    for (int q = 0; q < 16; ++q) wb[q] = *(const float4*)(hW3 + r*HH + 64 + 4*q);
    int gidx = 128 + r; int d = gidx >> 4, h0 = (gidx & 15) * 8;
    #pragma unroll
    for (int m = 0; m < 2; ++m) {
      wg[m]     = *(const float4*)(gW1 + d*HH + h0 + 4*m);
      wg[2 + m] = *(const float4*)(gb1 + d*HH + h0 + 4*m);
      wg[4 + m] = *(const float4*)(gW2 + d*HH + h0 + 4*m);
    }
  }
  // wave0 extras (head biases)
  float f2ba=0.f, f2bb=0.f, h3ba=0.f, h3bb=0.f, fb3d=0.f, gb2d=0.f, hb4d=0.f;
  if (j < 64) {
    f2ba = fb2[2*l]; f2bb = fb2[2*l + 1];
    h3ba = hb3[2*l]; h3bb = hb3[2*l + 1];
    fb3d = fb3[dq_d]; gb2d = gb2[dq_d]; hb4d = hb4[dq_d];
  }
  // LDS fills
  if (role == 0) {
    #pragma unroll
    for (int d2 = 0; d2 < DD; ++d2) w3c[r][d2] = fW3[d2*HH + r];
  } else if (role == 1) {
    #pragma unroll
    for (int d2 = 0; d2 < DD; ++d2) w4c[r][d2] = hW4[d2*HH + r];
  }
  if (j < DD) zv[j] = xs[(size_t)b*DD + j];
  if (j < CC) ctxb[1][j] = ctx[((size_t)1*BB + b)*CC + j];

  const float dtc = tsv[1] - tsv[0];
  const float sdt = sqrtf(dtc);
  float nreg = 0.0f;
  if (j < 64 && dq_q == 0) nreg = noise[(size_t)b*DD + dq_d];
  float lqp = 0.0f;
  float fd_r = 0.f, gd_r = 0.f;
  __syncthreads();

  for (int i = 0; i < TT-1; ++i) {
    const int cur = (i + 1) & 1;
    const int nxt = i & 1;
    // ----- P0: f L1, h L1, g hidden; prefetch noise(i+1), ctx(i+2) -----
    float nnext = 0.0f;
    if (j < 64 && dq_q == 0 && (i + 1) < TT-1)
      nnext = noise[((size_t)(i+1)*BB + b)*DD + dq_d];
    float creg = 0.0f;
    if (role == 3 && r < CC) {
      int t2 = (i + 2 <= TT-1) ? (i + 2) : (TT-1);
      creg = ctx[((size_t)t2*BB + b)*CC + r];
    }
    if (role == 0) {
      float a = dotnq<4>(wa, zv) + dotnq<16>(wa + 4, ctxb[cur]);
      x1[r] = spf(bA + a);
    } else if (role == 2) {
      float a = dotnq<4>(wa, zv);
      hx1[r] = spf(bA + a);
    }
    if (role == 1 || role == 3) {
      int gidx = (role == 1) ? r : (128 + r);
      int d = gidx >> 4;
      float zd = zv[d];
      float ps = 0.f;
      #pragma unroll
      for (int m = 0; m < 2; ++m) {
        float4 w1v = wg[m], b1v = wg[2 + m], w2v = wg[4 + m];
        ps += spf(fmaf(zd, w1v.x, b1v.x)) * w2v.x;
        ps += spf(fmaf(zd, w1v.y, b1v.y)) * w2v.y;
        ps += spf(fmaf(zd, w1v.z, b1v.z)) * w2v.z;
        ps += spf(fmaf(zd, w1v.w, b1v.w)) * w2v.w;
      }
      ps += __shfl_xor(ps, 1);
      ps += __shfl_xor(ps, 2);
      ps += __shfl_xor(ps, 4);
      ps += __shfl_xor(ps, 8);
      if ((gidx & 15) == 0) gdpre[d] = ps;
    }
    __syncthreads();
    // ----- P1: f L2 halves, h L2 halves -----
    if (role == 0)      p2[0][r] = dotnq<16>(wb, x1);
    else if (role == 1) p2[1][r] = dotnq<16>(wa, x1 + 64);
    else if (role == 2) hp[0][r] = dotnq<16>(wa + 4, hx1);
    else                hp[1][r] = dotnq<16>(wa, hx1 + 64);
    __syncthreads();
    // ----- P2: x2 combine + fd head + z update (wave0); hx2 combine (s2) -----
    if (j < 64) {
      int r0 = 2*l, r1 = r0 + 1;
      float2 pa = *(const float2*)(&p2[0][r0]);
      float2 pb = *(const float2*)(&p2[1][r0]);
      x2s[r0] = spf(pa.x + pb.x + f2ba);
      x2s[r1] = spf(pa.y + pb.y + f2bb);
      float fa0 = 0.f, fa1 = 0.f;
      #pragma unroll
      for (int rr = 0; rr < 32; ++rr) {
        int ri = 4*rr + dq_q;
        if (rr & 1) fa1 = fmaf(w3c[ri][dq_d], x2s[ri], fa1);
        else        fa0 = fmaf(w3c[ri][dq_d], x2s[ri], fa0);
      }
      float facc = fa0 + fa1;
      facc += __shfl_xor(facc, 1);
      facc += __shfl_xor(facc, 2);
      if (dq_q == 0) {
        float fd = facc + fb3d;
        float gd = spf(gdpre[dq_d] + gb2d);
        float zpre = zv[dq_d];
        float znew = fmaf(fd, dtc, fmaf(gd, sdt * nreg, zpre));
        zv[dq_d] = znew;
        fd_r = fd; gd_r = gd;
        if (dq_d >= 8) {
          out[2 + ((size_t)(i+1)*BB + b)*8 + (dq_d - 8)] = znew;
          if (i == 0) out[2 + (size_t)b*8 + (dq_d - 8)] = zpre;
        }
      }
    } else if (role == 2) {
      hx2[r] = spf(hp[0][r] + hp[1][r] + bB);
    } else if (role == 3 && r < CC) {
      ctxb[nxt][r] = creg;
    }
    __syncthreads();
    // ----- P3: h L3 halves -----
    if (role == 2)      hq[0][r] = dotnq<16>(wb, hx2);
    else if (role == 3) hq[1][r] = dotnq<16>(wb, hx2 + 64);
    __syncthreads();
    // ----- P4: hx3 combine + hd head + u, dlq (wave0) -----
    if (j < 64) {
      int r0 = 2*l, r1 = r0 + 1;
      float2 qa = *(const float2*)(&hq[0][r0]);
      float2 qb = *(const float2*)(&hq[1][r0]);
      hx3[r0] = spf(qa.x + qb.x + h3ba);
      hx3[r1] = spf(qa.y + qb.y + h3bb);
      float ha0 = 0.f, ha1 = 0.f;
      #pragma unroll
      for (int rr = 0; rr < 32; ++rr) {
        int ri = 4*rr + dq_q;
        if (rr & 1) ha1 = fmaf(w4c[ri][dq_d], hx3[ri], ha1);
        else        ha0 = fmaf(w4c[ri][dq_d], hx3[ri], ha0);
      }
      float hacc = ha0 + ha1;
      hacc += __shfl_xor(hacc, 1);
      hacc += __shfl_xor(hacc, 2);
      if (dq_q == 0) {
        float hd = hacc + hb4d;
        float uu = (fd_r - hd) / (gd_r + 1e-7f);
        lqp = fmaf(0.5f * uu * uu, dtc, lqp);
      }
    }
    nreg = nnext;
    __syncthreads();
  }
  if (j < 64) {
    lqp += __shfl_xor(lqp, 1);
    lqp += __shfl_xor(lqp, 2);
    lqp += __shfl_xor(lqp, 4);
    lqp += __shfl_xor(lqp, 8);
    lqp += __shfl_xor(lqp, 16);
    lqp += __shfl_xor(lqp, 32);
    if (l == 0) atomicAdd(out + 1, lqp * (1.0f / 256.0f));
  }
}

// ---------------------------------------------------------------------------
// log_pxs reduction: sum over (t,b,o) of log_prob, / B. One block per t.
// ---------------------------------------------------------------------------
__global__ __launch_bounds__(256) void lp_kernel(const float* __restrict__ xs,
                                                 float* __restrict__ out)
{
  const int t = blockIdx.x;
  const int b = threadIdx.x;
  const float cst = 3.6862316527834183f;  // -log(0.01) - 0.5*log(2*pi)
  const float* xrow = xs + ((size_t)t*BB + b)*DD + 8;
  const float* zrow = out + 2 + ((size_t)t*BB + b)*8;
  float acc = 0.f;
  #pragma unroll
  for (int o = 0; o < 8; ++o) {
    float dd = (xrow[o] - zrow[o]) * 100.0f;
    acc += cst - 0.5f * dd * dd;
  }
  #pragma unroll
  for (int m = 1; m < 64; m <<= 1) acc += __shfl_xor(acc, m);
  __shared__ float wpart[4];
  int w = threadIdx.x >> 6;
  if ((threadIdx.x & 63) == 0) wpart[w] = acc;
  __syncthreads();
  if (threadIdx.x == 0)
    atomicAdd(out, (wpart[0] + wpart[1] + wpart[2] + wpart[3]) * (1.0f / 256.0f));
}

extern "C" void kernel_launch(void* const* d_in, const int* in_sizes, int n_in,
                              void* d_out, int out_size, void* d_ws, size_t ws_size,
                              hipStream_t stream) {
  const float* xs    = (const float*)d_in[0];
  const float* tsv   = (const float*)d_in[1];
  const float* noise = (const float*)d_in[2];
  const float* Wih   = (const float*)d_in[3];
  const float* Whh   = (const float*)d_in[4];
  const float* bih   = (const float*)d_in[5];
  const float* bhh   = (const float*)d_in[6];
  const float* encW  = (const float*)d_in[7];
  const float* encB  = (const float*)d_in[8];
  const float* fW1   = (const float*)d_in[9];
  const float* fb1   = (const float*)d_in[10];
  const float* fW2   = (const float*)d_in[11];
  const float* fb2   = (const float*)d_in[12];
  const float* fW3   = (const float*)d_in[13];
  const float* fb3   = (const float*)d_in[14];
  const float* hW1   = (const float*)d_in[15];
  const float* hb1   = (const float*)d_in[16];
  const float* hW2   = (const float*)d_in[17];
  const float* hb2   = (const float*)d_in[18];
  const float* hW3   = (const float*)d_in[19];
  const float* hb3   = (const float*)d_in[20];
  const float* hW4   = (const float*)d_in[21];
  const float* hb4   = (const float*)d_in[22];
  const float* gW1   = (const float*)d_in[23];
  const float* gb1   = (const float*)d_in[24];
  const float* gW2   = (const float*)d_in[25];
  const float* gb2   = (const float*)d_in[26];
  float* out = (float*)d_out;
  float* ctx = (float*)d_ws;   // T*B*C floats = 64 MiB

  hipMemsetAsync(d_out, 0, 2 * sizeof(float), stream);
  enc_kernel<<<BB, 384, 0, stream>>>(xs, Wih, Whh, bih, bhh, encW, encB, ctx);
  sde_kernel<<<BB, 512, 0, stream>>>(xs, tsv, noise,
                                     fW1, fb1, fW2, fb2, fW3, fb3,
                                     hW1, hb1, hW2, hb2, hW3, hb3, hW4, hb4,
                                     gW1, gb1, gW2, gb2, ctx, out);
  lp_kernel<<<TT, BB, 0, stream>>>(xs, out);
}